// Round 2
// baseline (403.399 us; speedup 1.0000x reference)
//
#include <hip/hip_runtime.h>
#include <hip/hip_cooperative_groups.h>

namespace cg = cooperative_groups;

#define NBINS  256
#define CLIPV  2560u       // max(40 * 16384 // 256, 1)
#define NTILES 1536
#define NBLK   1024        // cooperative grid: 4 blocks/CU x 256 CUs

typedef float fx4 __attribute__((ext_vector_type(4)));

// ws layout: [0, 384K) u8 LUT; [512K, +24M) idx plane (fallback path only)
#define IDX_OFF (512 * 1024)

// ---------------------------------------------------------------------------
// Fused CLAHE: phase A = per-tile hist -> clip -> scan -> u8 LUT (to ws),
// per-pixel u8 idx kept in VGPRs (16 u32/tile). grid.sync(). phase B = build
// 4KB LDS pair-table from the 9 neighbor LUTs, bilinear blend, f32 out.
// Blocks 0..511 own tiles {b, b+1024}; blocks 512..1023 own tile {b}.
// ---------------------------------------------------------------------------
__global__ __launch_bounds__(256, 4) void clahe_fused(
        const float* __restrict__ x, unsigned char* __restrict__ lut8,
        float* __restrict__ out) {
    const int tid = threadIdx.x;
    const int blk = blockIdx.x;

    __shared__ unsigned int hs[NBINS * 8];   // 8 KB: 8-way bin-major sub-hist
    __shared__ int          sc[2][NBINS];    // 2 KB: scan ping-pong
    __shared__ unsigned int wsum[4];
    __shared__ unsigned int ptab[4 * NBINS]; // 4 KB: {rp,cp} pair-table

    const int sub    = tid & 7;
    const int lane32 = tid & 31;   // float4 column within the tile row
    const int rgrp   = tid >> 5;   // 0..7 -> 8 rows per iteration

    unsigned idxA[16], idxB[16];

    // ---- phase A: histogram + LUT for one tile; idx plane stays in regs ----
    auto histTile = [&](int t, unsigned (&idxp)[16]) {
        #pragma unroll
        for (int k = 0; k < 8; ++k) hs[k * NBINS + tid] = 0u;
        __syncthreads();

        const int tx = t & 7, ty = (t >> 3) & 7, bc = t >> 6;
        const float* base = x + ((size_t)bc * 1024 + (size_t)ty * 128) * 1024
                              + (size_t)tx * 128;
        #pragma unroll
        for (int rr = 0; rr < 16; ++rr) {      // FULL unroll: idxp[] static
            const int row = rr * 8 + rgrp;
            const fx4 v = __builtin_nontemporal_load(
                (const fx4*)(base + (size_t)row * 1024 + lane32 * 4));
            const int b0 = min(max((int)(v.x * 256.0f), 0), 255);
            const int b1 = min(max((int)(v.y * 256.0f), 0), 255);
            const int b2 = min(max((int)(v.z * 256.0f), 0), 255);
            const int b3 = min(max((int)(v.w * 256.0f), 0), 255);
            atomicAdd(&hs[b0 * 8 + sub], 1u);
            atomicAdd(&hs[b1 * 8 + sub], 1u);
            atomicAdd(&hs[b2 * 8 + sub], 1u);
            atomicAdd(&hs[b3 * 8 + sub], 1u);
            const unsigned i0 = (unsigned)min(max((int)(v.x * 255.0f), 0), 255);
            const unsigned i1 = (unsigned)min(max((int)(v.y * 255.0f), 0), 255);
            const unsigned i2 = (unsigned)min(max((int)(v.z * 255.0f), 0), 255);
            const unsigned i3 = (unsigned)min(max((int)(v.w * 255.0f), 0), 255);
            idxp[rr] = i0 | (i1 << 8) | (i2 << 16) | (i3 << 24);
        }
        __syncthreads();

        // gather 8 sub-counts for bin `tid`
        const uint4* hp = (const uint4*)(&hs[tid * 8]);
        const uint4 ha = hp[0], hb = hp[1];
        const unsigned int total = ha.x + ha.y + ha.z + ha.w
                                 + hb.x + hb.y + hb.z + hb.w;
        const unsigned int hv = min(total, CLIPV);
        unsigned int e = total - hv;
        #pragma unroll
        for (int off = 32; off > 0; off >>= 1) e += __shfl_down(e, off, 64);
        if ((tid & 63) == 0) wsum[tid >> 6] = e;
        __syncthreads();
        const unsigned int E        = wsum[0] + wsum[1] + wsum[2] + wsum[3];
        const unsigned int add      = E >> 8;
        const unsigned int residual = E & 255u;
        const int h2 = (int)(hv + add + ((unsigned)tid < residual ? 1u : 0u));

        sc[0][tid] = h2;
        __syncthreads();
        int src = 0;
        #pragma unroll
        for (int off = 1; off < 256; off <<= 1) {
            int v = sc[src][tid];
            if (tid >= off) v += sc[src][tid - off];
            sc[src ^ 1][tid] = v;
            __syncthreads();
            src ^= 1;
        }
        const int cum = sc[src][tid];
        const float l = fminf((float)cum * (255.0f / 16384.0f), 255.0f);
        lut8[(size_t)t * NBINS + tid] = (unsigned char)floorf(l);
        __syncthreads();   // all LDS reads done before next tile's writes
    };

    // ---- phase B: pair-table + bilinear apply; pixels from idx regs ----
    auto applyTile = [&](int t, unsigned (&idxp)[16]) {
        const int tx = t & 7, ty = (t >> 3) & 7, bc = t >> 6;

        __syncthreads();   // protect ptab against previous tile's readers
        {
            const unsigned char* lutP = lut8 + (size_t)bc * 64 * NBINS;
            const int ra0 = max(ty - 1, 0), ra1 = min(ra0 + 1, 7);  // rpair 0
            const int rb0 = ty,             rb1 = min(ty + 1, 7);   // rpair 1
            const int ca0 = max(tx - 1, 0), ca1 = min(ca0 + 1, 7);  // cpair 0
            const int cb0 = tx,             cb1 = min(tx + 1, 7);   // cpair 1
            const int R0[2] = {ra0, rb0}, R1[2] = {ra1, rb1};
            const int C0[2] = {ca0, cb0}, C1[2] = {ca1, cb1};
            #pragma unroll
            for (int rp = 0; rp < 2; ++rp)
                #pragma unroll
                for (int cp = 0; cp < 2; ++cp) {
                    const unsigned g00 = lutP[(R0[rp] * 8 + C0[cp]) * NBINS + tid];
                    const unsigned g01 = lutP[(R0[rp] * 8 + C1[cp]) * NBINS + tid];
                    const unsigned g10 = lutP[(R1[rp] * 8 + C0[cp]) * NBINS + tid];
                    const unsigned g11 = lutP[(R1[rp] * 8 + C1[cp]) * NBINS + tid];
                    ptab[(rp * 2 + cp) * NBINS + tid] =
                        g00 | (g01 << 8) | (g10 << 16) | (g11 << 24);
                }
        }
        __syncthreads();

        // column-axis params for this thread's 4 columns
        int   cbase[4];
        float wxk[4];
        #pragma unroll
        for (int k = 0; k < 4; ++k) {
            const int cx = lane32 * 4 + k;
            const int cp = cx >> 6;          // 0/1 -> cpair
            const int pc = cx & 63;
            cbase[k] = cp * NBINS;
            wxk[k] = (tx == 0 && cp == 0) ? 1.0f
                   : (float)(cp ? (127 - pc) : (63 - pc)) / 127.0f;
        }

        float* obase = out + ((size_t)bc * 1024 + (size_t)ty * 128) * 1024
                           + (size_t)tx * 128;
        #pragma unroll
        for (int rr = 0; rr < 16; ++rr) {     // FULL unroll: idxp[] static
            const int row = rr * 8 + rgrp;
            const int rp  = (rr >= 8) ? 1 : 0;     // row>>6, static per rr
            const int p   = row & 63;
            const float wy = (ty == 0 && rp == 0) ? 1.0f
                           : (float)(rp ? (127 - p) : (63 - p)) / 127.0f;
            const unsigned pk = idxp[rr];
            float res[4];
            #pragma unroll
            for (int k = 0; k < 4; ++k) {
                const unsigned id = (pk >> (8 * k)) & 0xffu;
                const unsigned e = ptab[rp * (2 * NBINS) + cbase[k] + id];
                const float g00 = (float)(e & 0xffu);
                const float g01 = (float)((e >> 8) & 0xffu);
                const float g10 = (float)((e >> 16) & 0xffu);
                const float g11 = (float)(e >> 24);
                const float wx = wxk[k];
                const float a = fmaf(wx, g00 - g01, g01);
                const float b = fmaf(wx, g10 - g11, g11);
                res[k] = fmaf(wy, a - b, b) * (1.0f / 255.0f);
            }
            const fx4 o4 = {res[0], res[1], res[2], res[3]};
            __builtin_nontemporal_store(
                o4, (fx4*)(obase + (size_t)row * 1024 + lane32 * 4));
        }
    };

    const bool has2 = (blk < NTILES - NBLK);   // blocks 0..511 own 2 tiles

    histTile(blk, idxA);
    if (has2) histTile(blk + NBLK, idxB);

    __threadfence();              // LUT writes visible device-scope
    cg::this_grid().sync();

    applyTile(blk, idxA);
    if (has2) applyTile(blk + NBLK, idxB);
}

// ---------------------------------------------------------------------------
// Fallback path (verified round-1 kernels) in case cooperative launch is
// rejected (e.g. by graph capture). Unchanged from the 180.2 µs baseline.
// ---------------------------------------------------------------------------
__global__ __launch_bounds__(256) void clahe_hist_lut(
        const float* __restrict__ x, unsigned char* __restrict__ lut8,
        unsigned int* __restrict__ idxw) {
    const int t   = blockIdx.x;
    const int tid = threadIdx.x;

    __shared__ unsigned int hs[NBINS * 8];
    __shared__ int          scan[2][NBINS];
    __shared__ unsigned int wsum[4];

    #pragma unroll
    for (int k = 0; k < 8; ++k) hs[k * NBINS + tid] = 0u;
    __syncthreads();

    const int tx = t & 7;
    const int ty = (t >> 3) & 7;
    const int bc = t >> 6;
    const size_t pbase = ((size_t)bc * 1024 + (size_t)ty * 128) * 1024
                       + (size_t)tx * 128;
    const float* base = x + pbase;

    const int sub    = tid & 7;
    const int lane32 = tid & 31;
    const int rgrp   = tid >> 5;
    #pragma unroll 4
    for (int rr = 0; rr < 16; ++rr) {
        const int row = rr * 8 + rgrp;
        const fx4 v = __builtin_nontemporal_load(
            (const fx4*)(base + (size_t)row * 1024 + lane32 * 4));
        const int b0 = min(max((int)(v.x * 256.0f), 0), 255);
        const int b1 = min(max((int)(v.y * 256.0f), 0), 255);
        const int b2 = min(max((int)(v.z * 256.0f), 0), 255);
        const int b3 = min(max((int)(v.w * 256.0f), 0), 255);
        atomicAdd(&hs[b0 * 8 + sub], 1u);
        atomicAdd(&hs[b1 * 8 + sub], 1u);
        atomicAdd(&hs[b2 * 8 + sub], 1u);
        atomicAdd(&hs[b3 * 8 + sub], 1u);
        const unsigned i0 = (unsigned)min(max((int)(v.x * 255.0f), 0), 255);
        const unsigned i1 = (unsigned)min(max((int)(v.y * 255.0f), 0), 255);
        const unsigned i2 = (unsigned)min(max((int)(v.z * 255.0f), 0), 255);
        const unsigned i3 = (unsigned)min(max((int)(v.w * 255.0f), 0), 255);
        idxw[(pbase + (size_t)row * 1024 + lane32 * 4) >> 2] =
            i0 | (i1 << 8) | (i2 << 16) | (i3 << 24);
    }
    __syncthreads();

    const uint4* hp = (const uint4*)(&hs[tid * 8]);
    const uint4 ha = hp[0], hb = hp[1];
    const unsigned int total = ha.x + ha.y + ha.z + ha.w
                             + hb.x + hb.y + hb.z + hb.w;
    const unsigned int hv = min(total, CLIPV);
    unsigned int e = total - hv;
    #pragma unroll
    for (int off = 32; off > 0; off >>= 1) e += __shfl_down(e, off, 64);
    if ((tid & 63) == 0) wsum[tid >> 6] = e;
    __syncthreads();
    const unsigned int E        = wsum[0] + wsum[1] + wsum[2] + wsum[3];
    const unsigned int add      = E >> 8;
    const unsigned int residual = E & 255u;
    const int h2 = (int)(hv + add + ((unsigned)tid < residual ? 1u : 0u));

    scan[0][tid] = h2;
    __syncthreads();
    int src = 0;
    #pragma unroll
    for (int off = 1; off < 256; off <<= 1) {
        int v = scan[src][tid];
        if (tid >= off) v += scan[src][tid - off];
        scan[src ^ 1][tid] = v;
        __syncthreads();
        src ^= 1;
    }
    const int cum = scan[src][tid];
    const float l = fminf((float)cum * (255.0f / 16384.0f), 255.0f);
    lut8[(size_t)t * NBINS + tid] = (unsigned char)floorf(l);
}

__global__ __launch_bounds__(256) void clahe_apply(
        const unsigned int* __restrict__ idxr,
        const unsigned char* __restrict__ lut8,
        float* __restrict__ out) {
    __shared__ unsigned int ptab[8 * NBINS];

    const int blk = blockIdx.x;
    const int bc  = blk >> 6;
    const int rg  = blk & 63;
    const int y0  = rg * 16;
    const int tid = threadIdx.x;

    const int j = y0 >> 6;
    int r0 = (j - 1) >> 1;
    r0 = min(max(r0, 0), 7);
    const int r1 = min(r0 + 1, 7);

    {
        const unsigned char* L0 = lut8 + (size_t)bc * 64 * NBINS + (size_t)r0 * 8 * NBINS;
        const unsigned char* L1 = lut8 + (size_t)bc * 64 * NBINS + (size_t)r1 * 8 * NBINS;
        unsigned a0[8], a1[8];
        #pragma unroll
        for (int c = 0; c < 8; ++c) {
            a0[c] = L0[c * NBINS + tid];
            a1[c] = L1[c * NBINS + tid];
        }
        #pragma unroll
        for (int c0 = 0; c0 < 8; ++c0) {
            const int c1 = min(c0 + 1, 7);
            ptab[c0 * NBINS + tid] =
                a0[c0] | (a0[c1] << 8) | (a1[c0] << 16) | (a1[c1] << 24);
        }
    }
    __syncthreads();

    int ock[4];
    float wxk[4];
    #pragma unroll
    for (int k = 0; k < 4; ++k) {
        const int xx = tid * 4 + k;
        const int jc = xx >> 6, pc = xx & 63;
        int c0 = (jc - 1) >> 1;
        c0 = min(max(c0, 0), 7);
        ock[k] = c0 * NBINS;
        wxk[k] = (jc == 0) ? 1.0f
               : (float)((jc & 1) ? (127 - pc) : (63 - pc)) / 127.0f;
    }

    const bool jzero = (j == 0);
    const bool jodd  = (j & 1);
    const size_t rowbase = ((size_t)bc * 1024 + (size_t)y0) * 1024 + tid * 4;

    #pragma unroll 4
    for (int r = 0; r < 16; ++r) {
        const int p = (y0 + r) & 63;
        const float wy = jzero ? 1.0f
                       : (float)(jodd ? (127 - p) : (63 - p)) / 127.0f;

        const unsigned pk = idxr[(rowbase + (size_t)r * 1024) >> 2];
        float res[4];
        #pragma unroll
        for (int k = 0; k < 4; ++k) {
            const unsigned id = (pk >> (8 * k)) & 0xffu;
            const unsigned e = ptab[ock[k] + id];
            const float g00 = (float)(e & 0xffu);
            const float g01 = (float)((e >> 8) & 0xffu);
            const float g10 = (float)((e >> 16) & 0xffu);
            const float g11 = (float)(e >> 24);
            const float wx = wxk[k];
            const float a = fmaf(wx, g00 - g01, g01);
            const float b = fmaf(wx, g10 - g11, g11);
            res[k] = fmaf(wy, a - b, b) * (1.0f / 255.0f);
        }
        const fx4 o4 = {res[0], res[1], res[2], res[3]};
        __builtin_nontemporal_store(
            o4, (fx4*)(out + rowbase + (size_t)r * 1024));
    }
}

extern "C" void kernel_launch(void* const* d_in, const int* in_sizes, int n_in,
                              void* d_out, int out_size, void* d_ws, size_t ws_size,
                              hipStream_t stream) {
    const float* x = (const float*)d_in[0];
    float* out = (float*)d_out;
    unsigned char* lut8 = (unsigned char*)d_ws;                  // 384 KB

    void* args[] = { (void*)&x, (void*)&lut8, (void*)&out };
    hipError_t err = hipLaunchCooperativeKernel(
        reinterpret_cast<const void*>(clahe_fused),
        dim3(NBLK), dim3(256), args, 0, stream);

    if (err != hipSuccess) {
        // graph-capture or co-residency rejection: verified 2-kernel path
        unsigned int* idxw = (unsigned int*)((char*)d_ws + IDX_OFF);
        clahe_hist_lut<<<1536, 256, 0, stream>>>(x, lut8, idxw);
        clahe_apply<<<24 * 64, 256, 0, stream>>>(idxw, lut8, out);
    }
}

// Round 6
// 396.260 us; speedup vs baseline: 1.0180x; 1.0180x over previous
//
#include <hip/hip_runtime.h>
#include <hip/hip_cooperative_groups.h>

namespace cg = cooperative_groups;

#define NBINS  256
#define CLIPV  2560u       // max(40 * 16384 // 256, 1)
#define NTILES 1536        // one block per tile, cooperative co-resident

typedef float fx4 __attribute__((ext_vector_type(4)));

// ws layout: [0, 384K) u8 LUT; [512K, +24M) idx plane (fallback path only)
#define IDX_OFF (512 * 1024)

// ---------------------------------------------------------------------------
// Fused CLAHE, take 2: per-pixel u8 idx lives in LDS (16 KB/block), NOT VGPRs
// (round-2 spill disaster: VGPR=64 + 32-dword arrays -> scratch, 264 us).
// LDS map (dwords), 24.6 KB total -> 6 blocks/CU -> all 1536 co-resident:
//   idx32 [0,4096)        u8 idx plane, packed 4 px/dword, whole kernel
//   hs    [4096,6144)     phase A: 8-way sub-hist (8 KB)
//     sc  [4096,4608)     scan ping-pong  (aliases hs AFTER gather barrier)
//     ptab[4096,5120)     phase B pair-table (aliases hs after grid.sync)
//   wsum  [6144,6148)
// ---------------------------------------------------------------------------
__global__ __launch_bounds__(256, 6) void clahe_fused(
        const float* __restrict__ x, unsigned char* __restrict__ lut8,
        float* __restrict__ out) {
    __shared__ unsigned int shm[6148];
    unsigned int* idx32 = shm;
    unsigned int* hs    = shm + 4096;
    unsigned int* wsum  = shm + 6144;

    const int tid = threadIdx.x;
    const int t   = blockIdx.x;          // tile id: ((b*3+c)*8+ty)*8+tx
    const int tx  = t & 7, ty = (t >> 3) & 7, bc = t >> 6;

    const int sub    = tid & 7;
    const int lane32 = tid & 31;   // float4 column within the tile row
    const int rgrp   = tid >> 5;   // 0..7 -> 8 rows per iteration

    // ================= phase A: histogram + idx(LDS) + LUT =================
    #pragma unroll
    for (int k = 0; k < 8; ++k) hs[k * NBINS + tid] = 0u;
    __syncthreads();

    {
        const float* base = x + ((size_t)bc * 1024 + (size_t)ty * 128) * 1024
                              + (size_t)tx * 128;
        #pragma unroll 4
        for (int rr = 0; rr < 16; ++rr) {
            const int row = rr * 8 + rgrp;
            const fx4 v = __builtin_nontemporal_load(
                (const fx4*)(base + (size_t)row * 1024 + lane32 * 4));
            const int b0 = min(max((int)(v.x * 256.0f), 0), 255);
            const int b1 = min(max((int)(v.y * 256.0f), 0), 255);
            const int b2 = min(max((int)(v.z * 256.0f), 0), 255);
            const int b3 = min(max((int)(v.w * 256.0f), 0), 255);
            atomicAdd(&hs[b0 * 8 + sub], 1u);
            atomicAdd(&hs[b1 * 8 + sub], 1u);
            atomicAdd(&hs[b2 * 8 + sub], 1u);
            atomicAdd(&hs[b3 * 8 + sub], 1u);
            const unsigned i0 = (unsigned)min(max((int)(v.x * 255.0f), 0), 255);
            const unsigned i1 = (unsigned)min(max((int)(v.y * 255.0f), 0), 255);
            const unsigned i2 = (unsigned)min(max((int)(v.z * 255.0f), 0), 255);
            const unsigned i3 = (unsigned)min(max((int)(v.w * 255.0f), 0), 255);
            idx32[row * 32 + lane32] = i0 | (i1 << 8) | (i2 << 16) | (i3 << 24);
        }
    }
    __syncthreads();

    // gather 8 sub-counts for bin `tid` (last read of hs before sc aliases it)
    const uint4* hp = (const uint4*)(&hs[tid * 8]);
    const uint4 ha = hp[0], hb = hp[1];
    const unsigned int total = ha.x + ha.y + ha.z + ha.w
                             + hb.x + hb.y + hb.z + hb.w;
    const unsigned int hv = min(total, CLIPV);
    unsigned int e = total - hv;
    #pragma unroll
    for (int off = 32; off > 0; off >>= 1) e += __shfl_down(e, off, 64);
    if ((tid & 63) == 0) wsum[tid >> 6] = e;
    __syncthreads();                      // hs reads all complete past here
    const unsigned int E        = wsum[0] + wsum[1] + wsum[2] + wsum[3];
    const unsigned int add      = E >> 8;
    const unsigned int residual = E & 255u;
    const int h2 = (int)(hv + add + ((unsigned)tid < residual ? 1u : 0u));

    // inclusive 256-bin scan; sc aliases hs[0..512)
    int* sc = (int*)hs;
    sc[tid] = h2;
    __syncthreads();
    int src = 0;
    #pragma unroll
    for (int off = 1; off < 256; off <<= 1) {
        int v = sc[src * NBINS + tid];
        if (tid >= off) v += sc[src * NBINS + tid - off];
        sc[(src ^ 1) * NBINS + tid] = v;
        __syncthreads();
        src ^= 1;
    }
    const int cum = sc[src * NBINS + tid];
    const float l = fminf((float)cum * (255.0f / 16384.0f), 255.0f);
    lut8[(size_t)t * NBINS + tid] = (unsigned char)floorf(l);

    __syncthreads();
    __threadfence();              // LUT writes visible device-scope
    cg::this_grid().sync();

    // ================= phase B: pair-table + bilinear apply =================
    unsigned int* ptab = hs;      // 1024 dwords, aliases hs/sc (all done)
    {
        const unsigned char* lutP = lut8 + (size_t)bc * 64 * NBINS;
        const int ra0 = max(ty - 1, 0), ra1 = min(ra0 + 1, 7);  // rpair 0
        const int rb0 = ty,             rb1 = min(ty + 1, 7);   // rpair 1
        const int ca0 = max(tx - 1, 0), ca1 = min(ca0 + 1, 7);  // cpair 0
        const int cb0 = tx,             cb1 = min(tx + 1, 7);   // cpair 1
        const int R0[2] = {ra0, rb0}, R1[2] = {ra1, rb1};
        const int C0[2] = {ca0, cb0}, C1[2] = {ca1, cb1};
        #pragma unroll
        for (int rp = 0; rp < 2; ++rp)
            #pragma unroll
            for (int cp = 0; cp < 2; ++cp) {
                const unsigned g00 = lutP[(R0[rp] * 8 + C0[cp]) * NBINS + tid];
                const unsigned g01 = lutP[(R0[rp] * 8 + C1[cp]) * NBINS + tid];
                const unsigned g10 = lutP[(R1[rp] * 8 + C0[cp]) * NBINS + tid];
                const unsigned g11 = lutP[(R1[rp] * 8 + C1[cp]) * NBINS + tid];
                ptab[(rp * 2 + cp) * NBINS + tid] =
                    g00 | (g01 << 8) | (g10 << 16) | (g11 << 24);
            }
    }
    __syncthreads();

    // column-axis params for this thread's 4 columns
    int   cbase[4];
    float wxk[4];
    #pragma unroll
    for (int k = 0; k < 4; ++k) {
        const int cx = lane32 * 4 + k;
        const int cp = cx >> 6;          // 0/1 -> cpair
        const int pc = cx & 63;
        cbase[k] = cp * NBINS;
        wxk[k] = (tx == 0 && cp == 0) ? 1.0f
               : (float)(cp ? (127 - pc) : (63 - pc)) / 127.0f;
    }

    float* obase = out + ((size_t)bc * 1024 + (size_t)ty * 128) * 1024
                       + (size_t)tx * 128;
    #pragma unroll 4
    for (int rr = 0; rr < 16; ++rr) {
        const int row = rr * 8 + rgrp;
        const int rp  = (rr >= 8) ? 1 : 0;     // == row>>6, static per rr
        const int p   = row & 63;
        const float wy = (ty == 0 && rp == 0) ? 1.0f
                       : (float)(rp ? (127 - p) : (63 - p)) / 127.0f;
        const unsigned pk = idx32[row * 32 + lane32];
        float res[4];
        #pragma unroll
        for (int k = 0; k < 4; ++k) {
            const unsigned id = (pk >> (8 * k)) & 0xffu;
            const unsigned ee = ptab[rp * 512 + cbase[k] + id];
            const float g00 = (float)(ee & 0xffu);
            const float g01 = (float)((ee >> 8) & 0xffu);
            const float g10 = (float)((ee >> 16) & 0xffu);
            const float g11 = (float)(ee >> 24);
            const float wx = wxk[k];
            const float a = fmaf(wx, g00 - g01, g01);
            const float b = fmaf(wx, g10 - g11, g11);
            res[k] = fmaf(wy, a - b, b) * (1.0f / 255.0f);
        }
        const fx4 o4 = {res[0], res[1], res[2], res[3]};
        __builtin_nontemporal_store(
            o4, (fx4*)(obase + (size_t)row * 1024 + lane32 * 4));
    }
}

// ---------------------------------------------------------------------------
// Fallback path (verified round-1 kernels, 180.2 us) if cooperative launch
// is rejected.
// ---------------------------------------------------------------------------
__global__ __launch_bounds__(256) void clahe_hist_lut(
        const float* __restrict__ x, unsigned char* __restrict__ lut8,
        unsigned int* __restrict__ idxw) {
    const int t   = blockIdx.x;
    const int tid = threadIdx.x;

    __shared__ unsigned int hs[NBINS * 8];
    __shared__ int          scan[2][NBINS];
    __shared__ unsigned int wsum[4];

    #pragma unroll
    for (int k = 0; k < 8; ++k) hs[k * NBINS + tid] = 0u;
    __syncthreads();

    const int tx = t & 7;
    const int ty = (t >> 3) & 7;
    const int bc = t >> 6;
    const size_t pbase = ((size_t)bc * 1024 + (size_t)ty * 128) * 1024
                       + (size_t)tx * 128;
    const float* base = x + pbase;

    const int sub    = tid & 7;
    const int lane32 = tid & 31;
    const int rgrp   = tid >> 5;
    #pragma unroll 4
    for (int rr = 0; rr < 16; ++rr) {
        const int row = rr * 8 + rgrp;
        const fx4 v = __builtin_nontemporal_load(
            (const fx4*)(base + (size_t)row * 1024 + lane32 * 4));
        const int b0 = min(max((int)(v.x * 256.0f), 0), 255);
        const int b1 = min(max((int)(v.y * 256.0f), 0), 255);
        const int b2 = min(max((int)(v.z * 256.0f), 0), 255);
        const int b3 = min(max((int)(v.w * 256.0f), 0), 255);
        atomicAdd(&hs[b0 * 8 + sub], 1u);
        atomicAdd(&hs[b1 * 8 + sub], 1u);
        atomicAdd(&hs[b2 * 8 + sub], 1u);
        atomicAdd(&hs[b3 * 8 + sub], 1u);
        const unsigned i0 = (unsigned)min(max((int)(v.x * 255.0f), 0), 255);
        const unsigned i1 = (unsigned)min(max((int)(v.y * 255.0f), 0), 255);
        const unsigned i2 = (unsigned)min(max((int)(v.z * 255.0f), 0), 255);
        const unsigned i3 = (unsigned)min(max((int)(v.w * 255.0f), 0), 255);
        idxw[(pbase + (size_t)row * 1024 + lane32 * 4) >> 2] =
            i0 | (i1 << 8) | (i2 << 16) | (i3 << 24);
    }
    __syncthreads();

    const uint4* hp = (const uint4*)(&hs[tid * 8]);
    const uint4 ha = hp[0], hb = hp[1];
    const unsigned int total = ha.x + ha.y + ha.z + ha.w
                             + hb.x + hb.y + hb.z + hb.w;
    const unsigned int hv = min(total, CLIPV);
    unsigned int e = total - hv;
    #pragma unroll
    for (int off = 32; off > 0; off >>= 1) e += __shfl_down(e, off, 64);
    if ((tid & 63) == 0) wsum[tid >> 6] = e;
    __syncthreads();
    const unsigned int E        = wsum[0] + wsum[1] + wsum[2] + wsum[3];
    const unsigned int add      = E >> 8;
    const unsigned int residual = E & 255u;
    const int h2 = (int)(hv + add + ((unsigned)tid < residual ? 1u : 0u));

    scan[0][tid] = h2;
    __syncthreads();
    int src = 0;
    #pragma unroll
    for (int off = 1; off < 256; off <<= 1) {
        int v = scan[src][tid];
        if (tid >= off) v += scan[src][tid - off];
        scan[src ^ 1][tid] = v;
        __syncthreads();
        src ^= 1;
    }
    const int cum = scan[src][tid];
    const float l = fminf((float)cum * (255.0f / 16384.0f), 255.0f);
    lut8[(size_t)t * NBINS + tid] = (unsigned char)floorf(l);
}

__global__ __launch_bounds__(256) void clahe_apply(
        const unsigned int* __restrict__ idxr,
        const unsigned char* __restrict__ lut8,
        float* __restrict__ out) {
    __shared__ unsigned int ptab[8 * NBINS];

    const int blk = blockIdx.x;
    const int bc  = blk >> 6;
    const int rg  = blk & 63;
    const int y0  = rg * 16;
    const int tid = threadIdx.x;

    const int j = y0 >> 6;
    int r0 = (j - 1) >> 1;
    r0 = min(max(r0, 0), 7);
    const int r1 = min(r0 + 1, 7);

    {
        const unsigned char* L0 = lut8 + (size_t)bc * 64 * NBINS + (size_t)r0 * 8 * NBINS;
        const unsigned char* L1 = lut8 + (size_t)bc * 64 * NBINS + (size_t)r1 * 8 * NBINS;
        unsigned a0[8], a1[8];
        #pragma unroll
        for (int c = 0; c < 8; ++c) {
            a0[c] = L0[c * NBINS + tid];
            a1[c] = L1[c * NBINS + tid];
        }
        #pragma unroll
        for (int c0 = 0; c0 < 8; ++c0) {
            const int c1 = min(c0 + 1, 7);
            ptab[c0 * NBINS + tid] =
                a0[c0] | (a0[c1] << 8) | (a1[c0] << 16) | (a1[c1] << 24);
        }
    }
    __syncthreads();

    int ock[4];
    float wxk[4];
    #pragma unroll
    for (int k = 0; k < 4; ++k) {
        const int xx = tid * 4 + k;
        const int jc = xx >> 6, pc = xx & 63;
        int c0 = (jc - 1) >> 1;
        c0 = min(max(c0, 0), 7);
        ock[k] = c0 * NBINS;
        wxk[k] = (jc == 0) ? 1.0f
               : (float)((jc & 1) ? (127 - pc) : (63 - pc)) / 127.0f;
    }

    const bool jzero = (j == 0);
    const bool jodd  = (j & 1);
    const size_t rowbase = ((size_t)bc * 1024 + (size_t)y0) * 1024 + tid * 4;

    #pragma unroll 4
    for (int r = 0; r < 16; ++r) {
        const int p = (y0 + r) & 63;
        const float wy = jzero ? 1.0f
                       : (float)(jodd ? (127 - p) : (63 - p)) / 127.0f;

        const unsigned pk = idxr[(rowbase + (size_t)r * 1024) >> 2];
        float res[4];
        #pragma unroll
        for (int k = 0; k < 4; ++k) {
            const unsigned id = (pk >> (8 * k)) & 0xffu;
            const unsigned e = ptab[ock[k] + id];
            const float g00 = (float)(e & 0xffu);
            const float g01 = (float)((e >> 8) & 0xffu);
            const float g10 = (float)((e >> 16) & 0xffu);
            const float g11 = (float)(e >> 24);
            const float wx = wxk[k];
            const float a = fmaf(wx, g00 - g01, g01);
            const float b = fmaf(wx, g10 - g11, g11);
            res[k] = fmaf(wy, a - b, b) * (1.0f / 255.0f);
        }
        const fx4 o4 = {res[0], res[1], res[2], res[3]};
        __builtin_nontemporal_store(
            o4, (fx4*)(out + rowbase + (size_t)r * 1024));
    }
}

extern "C" void kernel_launch(void* const* d_in, const int* in_sizes, int n_in,
                              void* d_out, int out_size, void* d_ws, size_t ws_size,
                              hipStream_t stream) {
    const float* x = (const float*)d_in[0];
    float* out = (float*)d_out;
    unsigned char* lut8 = (unsigned char*)d_ws;                  // 384 KB

    void* args[] = { (void*)&x, (void*)&lut8, (void*)&out };
    hipError_t err = hipLaunchCooperativeKernel(
        reinterpret_cast<const void*>(clahe_fused),
        dim3(NTILES), dim3(256), args, 0, stream);

    if (err != hipSuccess) {
        // co-residency or capture rejection: verified 2-kernel path
        unsigned int* idxw = (unsigned int*)((char*)d_ws + IDX_OFF);
        clahe_hist_lut<<<1536, 256, 0, stream>>>(x, lut8, idxw);
        clahe_apply<<<24 * 64, 256, 0, stream>>>(idxw, lut8, out);
    }
}

// Round 7
// 179.768 us; speedup vs baseline: 2.2440x; 2.2043x over previous
//
#include <hip/hip_runtime.h>

#define NBINS 256
#define TILE  128          // tile is 128x128 -> 16384 pixels
#define CLIPV 2560u        // max(40 * 16384 // 256, 1)

typedef float fx4 __attribute__((ext_vector_type(4)));   // native vec for nontemporal ops

// ws layout: [0, 384K)   u8 LUT, 1536 tiles x 256 bins
//            [512K, +24M) u8 idx plane, same linear layout as x
#define IDX_OFF (512 * 1024)

// ---------------------------------------------------------------------------
// Kernel 1: per-tile histogram -> clip -> redistribute -> cumsum -> u8 LUT,
// and emit the per-pixel u8 idx plane (so apply never re-reads f32 x).
// One block per tile (1536), 256 threads (4 waves).
// 8-way bin-major sub-histograms: hs[bin*8 + (tid&7)] -> bank 8*(bin%4)+sub,
// exactly 2 lanes/bank expected (free per m136).
// NOTE (r2/r6): cooperative fusion of K1+K2 measured 264us (VGPR idx, spills)
// and 206us (LDS idx, no spills) vs ~56us for this 2-kernel path — the
// grid.sync + device fence across 8 XCDs costs more than the 24MB idx
// round trip, which L3 (256MB) already absorbs. Fusion refuted; keep split.
// ---------------------------------------------------------------------------
__global__ __launch_bounds__(256) void clahe_hist_lut(
        const float* __restrict__ x, unsigned char* __restrict__ lut8,
        unsigned int* __restrict__ idxw) {
    const int t   = blockIdx.x;          // tile id: ((b*3+c)*8+ty)*8+tx
    const int tid = threadIdx.x;

    __shared__ unsigned int hs[NBINS * 8];   // bin-major interleaved
    __shared__ int          scan[2][NBINS];
    __shared__ unsigned int wsum[4];

    #pragma unroll
    for (int k = 0; k < 8; ++k) hs[k * NBINS + tid] = 0u;
    __syncthreads();

    const int tx = t & 7;
    const int ty = (t >> 3) & 7;
    const int bc = t >> 6;
    const size_t pbase = ((size_t)bc * 1024 + (size_t)ty * TILE) * 1024
                       + (size_t)tx * TILE;
    const float* base = x + pbase;

    const int sub    = tid & 7;
    const int lane32 = tid & 31;   // float4 column within the tile row
    const int rgrp   = tid >> 5;   // 0..7 -> 8 rows covered per iteration
    #pragma unroll 4
    for (int rr = 0; rr < 16; ++rr) {
        const int row = rr * 8 + rgrp;
        const fx4 v = __builtin_nontemporal_load(
            (const fx4*)(base + (size_t)row * 1024 + lane32 * 4));
        const int b0 = min(max((int)(v.x * 256.0f), 0), 255);
        const int b1 = min(max((int)(v.y * 256.0f), 0), 255);
        const int b2 = min(max((int)(v.z * 256.0f), 0), 255);
        const int b3 = min(max((int)(v.w * 256.0f), 0), 255);
        atomicAdd(&hs[b0 * 8 + sub], 1u);
        atomicAdd(&hs[b1 * 8 + sub], 1u);
        atomicAdd(&hs[b2 * 8 + sub], 1u);
        atomicAdd(&hs[b3 * 8 + sub], 1u);
        // idx plane (u8): clip(x*255); packed 4 pixels -> one dword store
        const unsigned i0 = (unsigned)min(max((int)(v.x * 255.0f), 0), 255);
        const unsigned i1 = (unsigned)min(max((int)(v.y * 255.0f), 0), 255);
        const unsigned i2 = (unsigned)min(max((int)(v.z * 255.0f), 0), 255);
        const unsigned i3 = (unsigned)min(max((int)(v.w * 255.0f), 0), 255);
        idxw[(pbase + (size_t)row * 1024 + lane32 * 4) >> 2] =
            i0 | (i1 << 8) | (i2 << 16) | (i3 << 24);
    }
    __syncthreads();

    // gather the 8 sub-counts for bin `tid`
    const uint4* hp = (const uint4*)(&hs[tid * 8]);
    const uint4 ha = hp[0], hb = hp[1];
    const unsigned int total = ha.x + ha.y + ha.z + ha.w
                             + hb.x + hb.y + hb.z + hb.w;
    const unsigned int hv = min(total, CLIPV);
    unsigned int e = total - hv;               // excess clipped from this bin
    #pragma unroll
    for (int off = 32; off > 0; off >>= 1) e += __shfl_down(e, off, 64);
    if ((tid & 63) == 0) wsum[tid >> 6] = e;
    __syncthreads();
    const unsigned int E        = wsum[0] + wsum[1] + wsum[2] + wsum[3];
    const unsigned int add      = E >> 8;      // (clipped - residual)/256
    const unsigned int residual = E & 255u;    // clipped mod 256
    const int h2 = (int)(hv + add + ((unsigned)tid < residual ? 1u : 0u));

    // inclusive scan over 256 bins (Hillis-Steele, ping-pong)
    scan[0][tid] = h2;
    __syncthreads();
    int src = 0;
    #pragma unroll
    for (int off = 1; off < 256; off <<= 1) {
        int v = scan[src][tid];
        if (tid >= off) v += scan[src][tid - off];
        scan[src ^ 1][tid] = v;
        __syncthreads();
        src ^= 1;
    }
    const int cum = scan[src][tid];
    // 255/16384 = 255 * 2^-14: fp32 multiply is exact here (cum*255 < 2^22)
    // result is an exact integer 0..255 -> u8
    const float l = fminf((float)cum * (255.0f / 16384.0f), 255.0f);
    lut8[(size_t)t * NBINS + tid] = (unsigned char)floorf(l);
}

// ---------------------------------------------------------------------------
// Kernel 2: bilinear LUT interpolation from the u8 idx plane.
// One block per (bc, 16-row group); (r0,r1) uniform over the group.
// LDS pair-table: ptab[c0*256+i] packs {l_r0[c0][i], l_r0[c1][i],
// l_r1[c0][i], l_r1[c1][i]} as 4 u8 in one u32 -> ALL FOUR bilinear taps are
// a single ds_read_b32 per pixel. wx=1 / wy=1 edges remain exact because the
// factored blend g01 + 1.0*(g00-g01) is exact for small integers.
// ---------------------------------------------------------------------------
__global__ __launch_bounds__(256) void clahe_apply(
        const unsigned int* __restrict__ idxr,
        const unsigned char* __restrict__ lut8,
        float* __restrict__ out) {
    __shared__ unsigned int ptab[8 * NBINS];

    const int blk = blockIdx.x;
    const int bc  = blk >> 6;          // 64 16-row groups per image plane
    const int rg  = blk & 63;
    const int y0  = rg * 16;
    const int tid = threadIdx.x;

    // row-axis interpolation coords (half = 64, denom = 127) — group-uniform
    const int j = y0 >> 6;
    int r0 = (j - 1) >> 1;             // matches Python floor division
    r0 = min(max(r0, 0), 7);
    const int r1 = min(r0 + 1, 7);

    // build the pair table: 16 coalesced byte loads + 8 LDS stores per thread
    {
        const unsigned char* L0 = lut8 + (size_t)bc * 64 * NBINS + (size_t)r0 * 8 * NBINS;
        const unsigned char* L1 = lut8 + (size_t)bc * 64 * NBINS + (size_t)r1 * 8 * NBINS;
        unsigned a0[8], a1[8];
        #pragma unroll
        for (int c = 0; c < 8; ++c) {
            a0[c] = L0[c * NBINS + tid];
            a1[c] = L1[c * NBINS + tid];
        }
        #pragma unroll
        for (int c0 = 0; c0 < 8; ++c0) {
            const int c1 = min(c0 + 1, 7);
            ptab[c0 * NBINS + tid] =
                a0[c0] | (a0[c1] << 8) | (a1[c0] << 16) | (a1[c1] << 24);
        }
    }
    __syncthreads();

    // column-axis params for this thread's 4 columns (fixed across rows)
    int ock[4];
    float wxk[4];
    #pragma unroll
    for (int k = 0; k < 4; ++k) {
        const int xx = tid * 4 + k;
        const int jc = xx >> 6, pc = xx & 63;
        int c0 = (jc - 1) >> 1;
        c0 = min(max(c0, 0), 7);
        ock[k] = c0 * NBINS;
        wxk[k] = (jc == 0) ? 1.0f
               : (float)((jc & 1) ? (127 - pc) : (63 - pc)) / 127.0f;
    }

    const bool jzero = (j == 0);
    const bool jodd  = (j & 1);
    const size_t rowbase = ((size_t)bc * 1024 + (size_t)y0) * 1024 + tid * 4;

    #pragma unroll 4
    for (int r = 0; r < 16; ++r) {
        const int p = (y0 + r) & 63;
        const float wy = jzero ? 1.0f
                       : (float)(jodd ? (127 - p) : (63 - p)) / 127.0f;

        const unsigned pk = idxr[(rowbase + (size_t)r * 1024) >> 2];
        float res[4];
        #pragma unroll
        for (int k = 0; k < 4; ++k) {
            const unsigned id = (pk >> (8 * k)) & 0xffu;
            const unsigned e = ptab[ock[k] + id];
            const float g00 = (float)(e & 0xffu);
            const float g01 = (float)((e >> 8) & 0xffu);
            const float g10 = (float)((e >> 16) & 0xffu);
            const float g11 = (float)(e >> 24);
            const float wx = wxk[k];
            const float a = fmaf(wx, g00 - g01, g01);  // row r0 interp
            const float b = fmaf(wx, g10 - g11, g11);  // row r1 interp
            res[k] = fmaf(wy, a - b, b) * (1.0f / 255.0f);
        }
        const fx4 o4 = {res[0], res[1], res[2], res[3]};
        __builtin_nontemporal_store(
            o4, (fx4*)(out + rowbase + (size_t)r * 1024));
    }
}

extern "C" void kernel_launch(void* const* d_in, const int* in_sizes, int n_in,
                              void* d_out, int out_size, void* d_ws, size_t ws_size,
                              hipStream_t stream) {
    const float* x = (const float*)d_in[0];
    float* out = (float*)d_out;
    unsigned char* lut8 = (unsigned char*)d_ws;                       // 384 KB
    unsigned int*  idxw = (unsigned int*)((char*)d_ws + IDX_OFF);     // 24 MB

    clahe_hist_lut<<<1536, 256, 0, stream>>>(x, lut8, idxw);
    // 24 planes * 64 sixteen-row groups = 1536 blocks
    clahe_apply<<<24 * 64, 256, 0, stream>>>(idxw, lut8, out);
}